// Round 5
// baseline (344.671 us; speedup 1.0000x reference)
//
#include <hip/hip_runtime.h>
#include <hip/hip_bf16.h>
#include <math.h>

// Problem constants
constexpr int B = 16;
constexpr int S = 2048;
constexpr int H = 1024;
constexpr int E = 2048;

// ---------------------------------------------------------------------------
// K1: fused matvec chain  u[b,:] = ((query[b]*W_q^T)*W_bil)*W_enc
// 32 blocks (2 per batch), 1024 threads. Stages synced with __syncthreads.
// No atomics anywhere -> bitwise deterministic across calls.
// ---------------------------------------------------------------------------
__global__ __launch_bounds__(1024)
void k_chain(const float* __restrict__ query,
             const float* __restrict__ W_q,
             const float* __restrict__ W_bil,
             const float* __restrict__ W_enc,
             float* __restrict__ u) {
    __shared__ float qv[H];        // 4KB  query row
    __shared__ float qp[H];        // 4KB  q_proj row
    __shared__ float qw[H];        // 4KB  qW row
    __shared__ float4 pr[1024];    // 16KB stripe-partial scratch
    int b = blockIdx.x >> 1;
    int ehalf = blockIdx.x & 1;    // which half of E this block produces
    int tid = threadIdx.x;
    int wave = tid >> 6, lane = tid & 63;

    qv[tid] = query[b * H + tid];
    __syncthreads();

    // ---- stage 1: qp[h] = dot(qv, W_q[h,:])  (wave per h, 64 h per wave)
    {
        const float4* qv4 = (const float4*)qv;
        for (int j = 0; j < 64; ++j) {
            int h = wave * 64 + j;
            const float4* wrow = (const float4*)(W_q + (size_t)h * H);
            float acc = 0.f;
            #pragma unroll
            for (int q4 = lane; q4 < H / 4; q4 += 64) {
                float4 w = wrow[q4];
                float4 x = qv4[q4];
                acc += w.x * x.x + w.y * x.y + w.z * x.z + w.w * x.w;
            }
            #pragma unroll
            for (int off = 32; off; off >>= 1) acc += __shfl_down(acc, off, 64);
            if (lane == 0) qp[h] = acc;
        }
    }
    __syncthreads();

    // ---- stage 2: qw[h] = sum_hp qp[hp] * W_bil[hp,h]  (4-way hp stripes)
    {
        int hs = tid >> 8;         // stripe 0..3
        int h4 = tid & 255;        // float4 column (H/4 = 256)
        float4 acc = {0.f, 0.f, 0.f, 0.f};
        for (int hp = hs; hp < H; hp += 4) {
            float s = qp[hp];      // LDS broadcast
            float4 w = ((const float4*)(W_bil + (size_t)hp * H))[h4];
            acc.x += s * w.x; acc.y += s * w.y; acc.z += s * w.z; acc.w += s * w.w;
        }
        pr[tid] = acc;             // pr[hs*256 + h4]
        __syncthreads();
        if (tid < 256) {
            float4 a0 = pr[tid], a1 = pr[256 + tid], a2 = pr[512 + tid], a3 = pr[768 + tid];
            float4 r;
            r.x = (a0.x + a1.x) + (a2.x + a3.x);
            r.y = (a0.y + a1.y) + (a2.y + a3.y);
            r.z = (a0.z + a1.z) + (a2.z + a3.z);
            r.w = (a0.w + a1.w) + (a2.w + a3.w);
            ((float4*)qw)[tid] = r;
        }
    }
    __syncthreads();

    // ---- stage 3: u[b,e] = sum_h qw[h] * W_enc[h,e]  (this block's E-half)
    {
        int hs = tid >> 8;                       // stripe 0..3
        int e4 = ehalf * 256 + (tid & 255);      // float4 column of E/4=512
        float4 acc = {0.f, 0.f, 0.f, 0.f};
        for (int h = hs; h < H; h += 4) {
            float s = qw[h];       // LDS broadcast
            float4 w = ((const float4*)(W_enc + (size_t)h * E))[e4];
            acc.x += s * w.x; acc.y += s * w.y; acc.z += s * w.z; acc.w += s * w.w;
        }
        pr[tid] = acc;
        __syncthreads();
        if (tid < 256) {
            float4 a0 = pr[tid], a1 = pr[256 + tid], a2 = pr[512 + tid], a3 = pr[768 + tid];
            float4 r;
            r.x = (a0.x + a1.x) + (a2.x + a3.x);
            r.y = (a0.y + a1.y) + (a2.y + a3.y);
            r.z = (a0.z + a1.z) + (a2.z + a3.z);
            r.w = (a0.w + a1.w) + (a2.w + a3.w);
            ((float4*)(u + (size_t)b * E))[ehalf * 256 + tid] = r;
        }
    }
}

// ---------------------------------------------------------------------------
// K2: scores[b,s] = mask ? dot(u[b,:], value[b,s,:]) : -inf
// Register-resident u fragment. 16 rows/block, 4 rows/wave, 2-row unroll
// -> 16 outstanding 1KB loads/wave. grid (S/16, B) = 2048 blocks.
// ---------------------------------------------------------------------------
__global__ void k_scores(const float* __restrict__ u,
                         const float* __restrict__ value,
                         const int* __restrict__ mask,
                         float* __restrict__ scores) {
    int b = blockIdx.y;
    int w = threadIdx.x >> 6;
    int lane = threadIdx.x & 63;
    const float4* u4 = (const float4*)(u + (size_t)b * E);
    float4 uu[8];
    #pragma unroll
    for (int i = 0; i < 8; ++i) uu[i] = u4[i * 64 + lane];
    int s0 = blockIdx.x * 16 + w * 4;
    #pragma unroll
    for (int r = 0; r < 4; r += 2) {
        int s = s0 + r;
        const float4* v0 = (const float4*)(value + ((size_t)(b * S + s)) * E);
        const float4* v1 = (const float4*)(value + ((size_t)(b * S + s + 1)) * E);
        float a0 = 0.f, a1 = 0.f;
        #pragma unroll
        for (int i = 0; i < 8; ++i) {
            float4 x0 = v0[i * 64 + lane];
            float4 x1 = v1[i * 64 + lane];
            a0 += x0.x * uu[i].x + x0.y * uu[i].y + x0.z * uu[i].z + x0.w * uu[i].w;
            a1 += x1.x * uu[i].x + x1.y * uu[i].y + x1.z * uu[i].z + x1.w * uu[i].w;
        }
        #pragma unroll
        for (int off = 32; off; off >>= 1) {
            a0 += __shfl_down(a0, off, 64);
            a1 += __shfl_down(a1, off, 64);
        }
        if (lane == 0) {
            scores[b * S + s]     = mask[b * S + s]     ? a0 : -INFINITY;
            scores[b * S + s + 1] = mask[b * S + s + 1] ? a1 : -INFINITY;
        }
    }
}

// ---------------------------------------------------------------------------
// K3: softmax + alphas + context, one block per batch (no cross-block deps).
// Skip bound: alpha <= 1e-8 rows contribute <= 2048*1e-8*max|v| ~ 1e-4
// << 7.75e-2 threshold. Threshold test is block-uniform (LDS value).
// ---------------------------------------------------------------------------
__global__ void k_smctx(const float* __restrict__ scores,
                        const float* __restrict__ value,
                        float* __restrict__ alphas,
                        float* __restrict__ context) {
    __shared__ float sc[S];        // 8KB
    __shared__ float red[256];
    int b = blockIdx.x;
    int tid = threadIdx.x;
    const float* srow = scores + b * S;
    float m = -INFINITY;
    for (int s = tid; s < S; s += 256) {
        float v = srow[s];
        sc[s] = v;
        m = fmaxf(m, v);
    }
    red[tid] = m;
    __syncthreads();
    for (int off = 128; off; off >>= 1) {
        if (tid < off) red[tid] = fmaxf(red[tid], red[tid + off]);
        __syncthreads();
    }
    m = red[0];
    __syncthreads();
    float l = 0.f;
    for (int s = tid; s < S; s += 256) {
        float p = __expf(sc[s] - m);
        sc[s] = p;
        l += p;
    }
    red[tid] = l;
    __syncthreads();
    for (int off = 128; off; off >>= 1) {
        if (tid < off) red[tid] += red[tid + off];
        __syncthreads();
    }
    float lsum = red[0];
    float inv = 1.f / lsum;
    float thresh = 1e-8f * lsum;    // p > thresh  <=>  alpha > 1e-8
    for (int s = tid; s < S; s += 256)
        alphas[b * S + s] = sc[s] * inv;
    __syncthreads();
    float4 acc0 = {0.f, 0.f, 0.f, 0.f}, acc1 = {0.f, 0.f, 0.f, 0.f};
    for (int s = 0; s < S; ++s) {
        float p = sc[s];
        if (p > thresh) {           // block-uniform -> no divergence
            const float4* vrow = (const float4*)(value + (size_t)(b * S + s) * E);
            float4 v0 = vrow[tid];
            float4 v1 = vrow[256 + tid];
            acc0.x += p * v0.x; acc0.y += p * v0.y; acc0.z += p * v0.z; acc0.w += p * v0.w;
            acc1.x += p * v1.x; acc1.y += p * v1.y; acc1.z += p * v1.z; acc1.w += p * v1.w;
        }
    }
    acc0.x *= inv; acc0.y *= inv; acc0.z *= inv; acc0.w *= inv;
    acc1.x *= inv; acc1.y *= inv; acc1.z *= inv; acc1.w *= inv;
    float4* ctx4 = (float4*)(context + (size_t)b * E);
    ctx4[tid] = acc0;
    ctx4[256 + tid] = acc1;
}

// ---------------------------------------------------------------------------
extern "C" void kernel_launch(void* const* d_in, const int* in_sizes, int n_in,
                              void* d_out, int out_size, void* d_ws, size_t ws_size,
                              hipStream_t stream) {
    const float* query = (const float*)d_in[0];   // [B,1,H]
    const float* value = (const float*)d_in[1];   // [B,S,E]
    const int*   mask  = (const int*)d_in[2];     // [B,1,S]
    const float* W_enc = (const float*)d_in[3];   // [H,E]
    const float* W_q   = (const float*)d_in[4];   // [H,H]
    const float* W_bil = (const float*)d_in[5];   // [H,H]

    float* out = (float*)d_out;
    float* context = out;          // [B,1,E]
    float* alphas  = out + B * E;  // [B,1,S]

    float* ws = (float*)d_ws;
    float* u     = ws;             // B*E floats
    float* sc_ws = ws + B * E;     // B*S floats

    // K1: fused q_proj -> qW -> u chain (no atomics, deterministic)
    k_chain<<<dim3(2 * B), 1024, 0, stream>>>(query, W_q, W_bil, W_enc, u);

    // K2: scores (the 268 MB HBM stream)
    k_scores<<<dim3(S / 16, B), 256, 0, stream>>>(u, value, mask, sc_ws);

    // K3: softmax + alphas + context
    k_smctx<<<dim3(B), 256, 0, stream>>>(sc_ws, value, alphas, context);
}

// Round 6
// 189.752 us; speedup vs baseline: 1.8164x; 1.8164x over previous
//
#include <hip/hip_runtime.h>
#include <hip/hip_bf16.h>
#include <math.h>

// Problem constants
constexpr int B = 16;
constexpr int S = 2048;
constexpr int H = 1024;
constexpr int E = 2048;

constexpr int KS = 8;              // split-K (H is split into 8 chunks of 128)
constexpr int CH = H / KS;         // 128 rows per chunk

// ---------------------------------------------------------------------------
// K1: per-chunk partial of the first two matvecs.
// grid (1, B, KS) = 128 blocks x 256 thr.
//  stage A (inline q_proj chunk): qp[j] = dot(query[b,:], W_q[z*128+j,:])
//  stage B: qwpart[z][b][h] = sum_{j in chunk} qp[j] * W_bil[z*128+j, h]
// No atomics -> deterministic.
// ---------------------------------------------------------------------------
__global__ void k_qw_part(const float* __restrict__ query,
                          const float* __restrict__ W_q,
                          const float* __restrict__ W_bil,
                          float* __restrict__ qwpart) {
    __shared__ float qv[H];     // 4KB query row
    __shared__ float qp[CH];    // q_proj chunk
    int b = blockIdx.y, z = blockIdx.z;
    int tid = threadIdx.x;
    int wave = tid >> 6, lane = tid & 63;

    ((float4*)qv)[tid] = ((const float4*)(query + (size_t)b * H))[tid];
    __syncthreads();

    // stage A: 4 waves x 32 dots each, dot length H (4 float4 iters/lane)
    const float4* qv4 = (const float4*)qv;
    for (int jj = 0; jj < CH / 4; ++jj) {
        int j = wave * (CH / 4) + jj;
        const float4* wrow = (const float4*)(W_q + (size_t)(z * CH + j) * H);
        float acc = 0.f;
        #pragma unroll
        for (int q4 = lane; q4 < H / 4; q4 += 64) {
            float4 w = wrow[q4];
            float4 x = qv4[q4];
            acc += w.x * x.x + w.y * x.y + w.z * x.z + w.w * x.w;
        }
        #pragma unroll
        for (int off = 32; off; off >>= 1) acc += __shfl_down(acc, off, 64);
        if (lane == 0) qp[j] = acc;
    }
    __syncthreads();

    // stage B: thread owns float4 column tid of H/4=256
    float4 acc = {0.f, 0.f, 0.f, 0.f};
    #pragma unroll 8
    for (int j = 0; j < CH; ++j) {
        float s = qp[j];
        float4 w = ((const float4*)(W_bil + (size_t)(z * CH + j) * H))[tid];
        acc.x += s * w.x; acc.y += s * w.y; acc.z += s * w.z; acc.w += s * w.w;
    }
    ((float4*)(qwpart + ((size_t)z * B + b) * H))[tid] = acc;
}

// ---------------------------------------------------------------------------
// K2: fused qW-reduce + u-partial.
// grid (E/1024=2, B, KS) = 256 blocks x 256 thr.
//  stage A: qw[j] = sum_z' qwpart[z'][b][z*128+j]   (reduce 8 partials)
//  stage B: upart[z][b][e] = sum_{j in chunk} qw[j] * W_enc[z*128+j, e]
// ---------------------------------------------------------------------------
__global__ void k_u_part(const float* __restrict__ qwpart,
                         const float* __restrict__ W_enc,
                         float* __restrict__ upart) {
    __shared__ float qw[CH];
    int b = blockIdx.y, z = blockIdx.z;
    int tid = threadIdx.x;
    if (tid < CH) {
        int h = z * CH + tid;
        float s = 0.f;
        #pragma unroll
        for (int zz = 0; zz < KS; ++zz)
            s += qwpart[((size_t)zz * B + b) * H + h];
        qw[tid] = s;
    }
    __syncthreads();
    int e4 = blockIdx.x * 256 + tid;    // float4 column of E/4=512
    float4 acc = {0.f, 0.f, 0.f, 0.f};
    #pragma unroll 8
    for (int j = 0; j < CH; ++j) {
        float s = qw[j];
        float4 w = ((const float4*)(W_enc + (size_t)(z * CH + j) * E))[e4];
        acc.x += s * w.x; acc.y += s * w.y; acc.z += s * w.z; acc.w += s * w.w;
    }
    ((float4*)(upart + ((size_t)z * B + b) * E))[e4] = acc;
}

// ---------------------------------------------------------------------------
// K3: u[b,e] = sum_z upart[z][b][e].  32 blocks x 256 thr (float4 elements).
// ---------------------------------------------------------------------------
__global__ void k_u_red(const float* __restrict__ upart,
                        float* __restrict__ u) {
    int idx = blockIdx.x * 256 + threadIdx.x;   // 0..B*E/4-1, = b*512 + e4
    float4 acc = {0.f, 0.f, 0.f, 0.f};
    #pragma unroll
    for (int z = 0; z < KS; ++z) {
        float4 p = ((const float4*)upart)[(size_t)z * (B * E / 4) + idx];
        acc.x += p.x; acc.y += p.y; acc.z += p.z; acc.w += p.w;
    }
    ((float4*)u)[idx] = acc;
}

// ---------------------------------------------------------------------------
// K4: scores[b,s] = mask ? dot(u[b,:], value[b,s,:]) : -inf
// Register-resident u fragment. 16 rows/block, 4 rows/wave, 2-row unroll
// -> 16 outstanding 1KB loads/wave. grid (S/16, B) = 2048 blocks.
// ---------------------------------------------------------------------------
__global__ void k_scores(const float* __restrict__ u,
                         const float* __restrict__ value,
                         const int* __restrict__ mask,
                         float* __restrict__ scores) {
    int b = blockIdx.y;
    int w = threadIdx.x >> 6;
    int lane = threadIdx.x & 63;
    const float4* u4 = (const float4*)(u + (size_t)b * E);
    float4 uu[8];
    #pragma unroll
    for (int i = 0; i < 8; ++i) uu[i] = u4[i * 64 + lane];
    int s0 = blockIdx.x * 16 + w * 4;
    #pragma unroll
    for (int r = 0; r < 4; r += 2) {
        int s = s0 + r;
        const float4* v0 = (const float4*)(value + ((size_t)(b * S + s)) * E);
        const float4* v1 = (const float4*)(value + ((size_t)(b * S + s + 1)) * E);
        float a0 = 0.f, a1 = 0.f;
        #pragma unroll
        for (int i = 0; i < 8; ++i) {
            float4 x0 = v0[i * 64 + lane];
            float4 x1 = v1[i * 64 + lane];
            a0 += x0.x * uu[i].x + x0.y * uu[i].y + x0.z * uu[i].z + x0.w * uu[i].w;
            a1 += x1.x * uu[i].x + x1.y * uu[i].y + x1.z * uu[i].z + x1.w * uu[i].w;
        }
        #pragma unroll
        for (int off = 32; off; off >>= 1) {
            a0 += __shfl_down(a0, off, 64);
            a1 += __shfl_down(a1, off, 64);
        }
        if (lane == 0) {
            scores[b * S + s]     = mask[b * S + s]     ? a0 : -INFINITY;
            scores[b * S + s + 1] = mask[b * S + s + 1] ? a1 : -INFINITY;
        }
    }
}

// ---------------------------------------------------------------------------
// K5: softmax + alphas + context, one block per batch.
// Skip bound: alpha <= 1e-8 rows contribute <= 2048*1e-8*max|v| ~ 1e-4
// << 7.75e-2 threshold. Threshold test is block-uniform (LDS value).
// ---------------------------------------------------------------------------
__global__ void k_smctx(const float* __restrict__ scores,
                        const float* __restrict__ value,
                        float* __restrict__ alphas,
                        float* __restrict__ context) {
    __shared__ float sc[S];        // 8KB
    __shared__ float red[256];
    int b = blockIdx.x;
    int tid = threadIdx.x;
    const float* srow = scores + b * S;
    float m = -INFINITY;
    for (int s = tid; s < S; s += 256) {
        float v = srow[s];
        sc[s] = v;
        m = fmaxf(m, v);
    }
    red[tid] = m;
    __syncthreads();
    for (int off = 128; off; off >>= 1) {
        if (tid < off) red[tid] = fmaxf(red[tid], red[tid + off]);
        __syncthreads();
    }
    m = red[0];
    __syncthreads();
    float l = 0.f;
    for (int s = tid; s < S; s += 256) {
        float p = __expf(sc[s] - m);
        sc[s] = p;
        l += p;
    }
    red[tid] = l;
    __syncthreads();
    for (int off = 128; off; off >>= 1) {
        if (tid < off) red[tid] += red[tid + off];
        __syncthreads();
    }
    float lsum = red[0];
    float inv = 1.f / lsum;
    float thresh = 1e-8f * lsum;    // p > thresh  <=>  alpha > 1e-8
    for (int s = tid; s < S; s += 256)
        alphas[b * S + s] = sc[s] * inv;
    __syncthreads();
    float4 acc0 = {0.f, 0.f, 0.f, 0.f}, acc1 = {0.f, 0.f, 0.f, 0.f};
    for (int s = 0; s < S; ++s) {
        float p = sc[s];
        if (p > thresh) {           // block-uniform -> no divergence
            const float4* vrow = (const float4*)(value + (size_t)(b * S + s) * E);
            float4 v0 = vrow[tid];
            float4 v1 = vrow[256 + tid];
            acc0.x += p * v0.x; acc0.y += p * v0.y; acc0.z += p * v0.z; acc0.w += p * v0.w;
            acc1.x += p * v1.x; acc1.y += p * v1.y; acc1.z += p * v1.z; acc1.w += p * v1.w;
        }
    }
    acc0.x *= inv; acc0.y *= inv; acc0.z *= inv; acc0.w *= inv;
    acc1.x *= inv; acc1.y *= inv; acc1.z *= inv; acc1.w *= inv;
    float4* ctx4 = (float4*)(context + (size_t)b * E);
    ctx4[tid] = acc0;
    ctx4[256 + tid] = acc1;
}

// ---------------------------------------------------------------------------
extern "C" void kernel_launch(void* const* d_in, const int* in_sizes, int n_in,
                              void* d_out, int out_size, void* d_ws, size_t ws_size,
                              hipStream_t stream) {
    const float* query = (const float*)d_in[0];   // [B,1,H]
    const float* value = (const float*)d_in[1];   // [B,S,E]
    const int*   mask  = (const int*)d_in[2];     // [B,1,S]
    const float* W_enc = (const float*)d_in[3];   // [H,E]
    const float* W_q   = (const float*)d_in[4];   // [H,H]
    const float* W_bil = (const float*)d_in[5];   // [H,H]

    float* out = (float*)d_out;
    float* context = out;          // [B,1,E]
    float* alphas  = out + B * E;  // [B,1,S]

    float* ws = (float*)d_ws;
    float* u      = ws;                            // B*E
    float* sc_ws  = ws + B * E;                    // B*S
    float* qwpart = ws + B * E + B * S;            // KS*B*H
    float* upart  = qwpart + KS * B * H;           // KS*B*E

    // Chain: partials + fused reduce (all deterministic, no atomics)
    k_qw_part<<<dim3(1, B, KS), 256, 0, stream>>>(query, W_q, W_bil, qwpart);
    k_u_part <<<dim3(E / 1024, B, KS), 256, 0, stream>>>(qwpart, W_enc, upart);
    k_u_red  <<<dim3(B * E / 1024), 256, 0, stream>>>(upart, u);

    // Scores (the 268 MB HBM stream)
    k_scores<<<dim3(S / 16, B), 256, 0, stream>>>(u, value, mask, sc_ws);

    // Softmax + alphas + context
    k_smctx<<<dim3(B), 256, 0, stream>>>(sc_ws, value, alphas, context);
}

// Round 7
// 184.082 us; speedup vs baseline: 1.8724x; 1.0308x over previous
//
#include <hip/hip_runtime.h>
#include <hip/hip_bf16.h>
#include <math.h>

// Problem constants
constexpr int B = 16;
constexpr int S = 2048;
constexpr int H = 1024;
constexpr int E = 2048;

constexpr int Z2 = 32;             // split of H for qW partials (32 rows each)
constexpr int C2 = H / Z2;         // 32
constexpr int Z3 = 16;             // split of H for u partials (64 rows each)
constexpr int C3 = H / Z3;         // 64

// ---------------------------------------------------------------------------
// K1: qwp[z][b][h] = sum_{j in 32-chunk z} qp[b,zC2+j] * W_bil[zC2+j, h]
// where qp rows are computed INLINE (8 dots per wave, 4-float4 ILP each).
// grid (H/256=4, B, Z2=32) = 2048 blocks x 256 thr -> 8 blocks/CU.
// x-blocks recompute the same 32 qp values redundantly (deterministic).
// ---------------------------------------------------------------------------
__global__ void k_qwp(const float* __restrict__ query,
                      const float* __restrict__ W_q,
                      const float* __restrict__ W_bil,
                      float* __restrict__ qwp) {
    __shared__ float lqp[C2];
    int b = blockIdx.y, z = blockIdx.z;
    int tid = threadIdx.x;
    int wave = tid >> 6, lane = tid & 63;

    // stage A: 32 dots of length H; wave w does j = w*8 .. w*8+7
    const float4* qrow = (const float4*)(query + (size_t)b * H);
    for (int jj = 0; jj < 8; ++jj) {
        int j = wave * 8 + jj;
        const float4* wrow = (const float4*)(W_q + (size_t)(z * C2 + j) * H);
        float acc = 0.f;
        #pragma unroll
        for (int i = 0; i < 4; ++i) {
            float4 w = wrow[i * 64 + lane];
            float4 x = qrow[i * 64 + lane];
            acc += w.x * x.x + w.y * x.y + w.z * x.z + w.w * x.w;
        }
        #pragma unroll
        for (int off = 32; off; off >>= 1) acc += __shfl_down(acc, off, 64);
        if (lane == 0) lqp[j] = acc;
    }
    __syncthreads();

    // stage B: fully unrolled 32-iter partial; coalesced W_bil row loads
    int h = blockIdx.x * 256 + tid;
    float acc = 0.f;
    #pragma unroll
    for (int j = 0; j < C2; ++j)
        acc += lqp[j] * W_bil[(size_t)(z * C2 + j) * H + h];
    qwp[((size_t)z * B + b) * H + h] = acc;
}

// ---------------------------------------------------------------------------
// K2: up[z][b][e] = sum_{j in 64-chunk z} qw[b,zC3+j] * W_enc[zC3+j, e]
// stage A reduces the 32 qwp partials for this chunk's 64 rows via LDS.
// grid (E/256=8, B, Z3=16) = 2048 blocks x 256 thr -> 8 blocks/CU.
// ---------------------------------------------------------------------------
__global__ void k_up(const float* __restrict__ qwp,
                     const float* __restrict__ W_enc,
                     float* __restrict__ up) {
    __shared__ float part[256];
    __shared__ float lqw[C3];
    int b = blockIdx.y, z = blockIdx.z;
    int tid = threadIdx.x;
    int h0 = z * C3;

    // stage A: qw[j] = sum_{zz<32} qwp[zz][b][h0+j]; t=(q*64+j), q sums 8 zz's
    {
        int j = tid & 63, q = tid >> 6;
        float s = 0.f;
        #pragma unroll
        for (int k = 0; k < 8; ++k) {
            int zz = q * 8 + k;
            s += qwp[((size_t)zz * B + b) * H + h0 + j];
        }
        part[tid] = s;
    }
    __syncthreads();
    if (tid < C3)
        lqw[tid] = (part[tid] + part[64 + tid]) + (part[128 + tid] + part[192 + tid]);
    __syncthreads();

    // stage B: 64-iter unrolled partial; coalesced W_enc row loads
    int e = blockIdx.x * 256 + tid;
    float acc = 0.f;
    #pragma unroll 16
    for (int j = 0; j < C3; ++j)
        acc += lqw[j] * W_enc[(size_t)(h0 + j) * E + e];
    up[((size_t)z * B + b) * E + e] = acc;
}

// ---------------------------------------------------------------------------
// K3: u = sum_z up[z].  128 blocks x 256 thr, 16 independent loads/thread.
// ---------------------------------------------------------------------------
__global__ void k_ured(const float* __restrict__ up,
                       float* __restrict__ u) {
    int idx = blockIdx.x * 256 + threadIdx.x;   // 0 .. B*E-1
    float acc = 0.f;
    #pragma unroll
    for (int z = 0; z < Z3; ++z)
        acc += up[(size_t)z * (B * E) + idx];
    u[idx] = acc;
}

// ---------------------------------------------------------------------------
// K4: scores[b,s] = mask ? dot(u[b,:], value[b,s,:]) : -inf
// Register-resident u fragment. 16 rows/block, 4 rows/wave, 2-row unroll
// -> 16 outstanding 1KB loads/wave. grid (S/16, B) = 2048 blocks. (proven)
// ---------------------------------------------------------------------------
__global__ void k_scores(const float* __restrict__ u,
                         const float* __restrict__ value,
                         const int* __restrict__ mask,
                         float* __restrict__ scores) {
    int b = blockIdx.y;
    int w = threadIdx.x >> 6;
    int lane = threadIdx.x & 63;
    const float4* u4 = (const float4*)(u + (size_t)b * E);
    float4 uu[8];
    #pragma unroll
    for (int i = 0; i < 8; ++i) uu[i] = u4[i * 64 + lane];
    int s0 = blockIdx.x * 16 + w * 4;
    #pragma unroll
    for (int r = 0; r < 4; r += 2) {
        int s = s0 + r;
        const float4* v0 = (const float4*)(value + ((size_t)(b * S + s)) * E);
        const float4* v1 = (const float4*)(value + ((size_t)(b * S + s + 1)) * E);
        float a0 = 0.f, a1 = 0.f;
        #pragma unroll
        for (int i = 0; i < 8; ++i) {
            float4 x0 = v0[i * 64 + lane];
            float4 x1 = v1[i * 64 + lane];
            a0 += x0.x * uu[i].x + x0.y * uu[i].y + x0.z * uu[i].z + x0.w * uu[i].w;
            a1 += x1.x * uu[i].x + x1.y * uu[i].y + x1.z * uu[i].z + x1.w * uu[i].w;
        }
        #pragma unroll
        for (int off = 32; off; off >>= 1) {
            a0 += __shfl_down(a0, off, 64);
            a1 += __shfl_down(a1, off, 64);
        }
        if (lane == 0) {
            scores[b * S + s]     = mask[b * S + s]     ? a0 : -INFINITY;
            scores[b * S + s + 1] = mask[b * S + s + 1] ? a1 : -INFINITY;
        }
    }
}

// ---------------------------------------------------------------------------
// K5: softmax + alphas + context, one block per batch. (proven R5/R6)
// Skip bound: alpha <= 1e-8 rows contribute <= 2048*1e-8*max|v| ~ 1e-4
// << 7.75e-2 threshold. Threshold test is block-uniform (LDS value).
// ---------------------------------------------------------------------------
__global__ void k_smctx(const float* __restrict__ scores,
                        const float* __restrict__ value,
                        float* __restrict__ alphas,
                        float* __restrict__ context) {
    __shared__ float sc[S];        // 8KB
    __shared__ float red[256];
    int b = blockIdx.x;
    int tid = threadIdx.x;
    const float* srow = scores + b * S;
    float m = -INFINITY;
    for (int s = tid; s < S; s += 256) {
        float v = srow[s];
        sc[s] = v;
        m = fmaxf(m, v);
    }
    red[tid] = m;
    __syncthreads();
    for (int off = 128; off; off >>= 1) {
        if (tid < off) red[tid] = fmaxf(red[tid], red[tid + off]);
        __syncthreads();
    }
    m = red[0];
    __syncthreads();
    float l = 0.f;
    for (int s = tid; s < S; s += 256) {
        float p = __expf(sc[s] - m);
        sc[s] = p;
        l += p;
    }
    red[tid] = l;
    __syncthreads();
    for (int off = 128; off; off >>= 1) {
        if (tid < off) red[tid] += red[tid + off];
        __syncthreads();
    }
    float lsum = red[0];
    float inv = 1.f / lsum;
    float thresh = 1e-8f * lsum;    // p > thresh  <=>  alpha > 1e-8
    for (int s = tid; s < S; s += 256)
        alphas[b * S + s] = sc[s] * inv;
    __syncthreads();
    float4 acc0 = {0.f, 0.f, 0.f, 0.f}, acc1 = {0.f, 0.f, 0.f, 0.f};
    for (int s = 0; s < S; ++s) {
        float p = sc[s];
        if (p > thresh) {           // block-uniform -> no divergence
            const float4* vrow = (const float4*)(value + (size_t)(b * S + s) * E);
            float4 v0 = vrow[tid];
            float4 v1 = vrow[256 + tid];
            acc0.x += p * v0.x; acc0.y += p * v0.y; acc0.z += p * v0.z; acc0.w += p * v0.w;
            acc1.x += p * v1.x; acc1.y += p * v1.y; acc1.z += p * v1.z; acc1.w += p * v1.w;
        }
    }
    acc0.x *= inv; acc0.y *= inv; acc0.z *= inv; acc0.w *= inv;
    acc1.x *= inv; acc1.y *= inv; acc1.z *= inv; acc1.w *= inv;
    float4* ctx4 = (float4*)(context + (size_t)b * E);
    ctx4[tid] = acc0;
    ctx4[256 + tid] = acc1;
}

// ---------------------------------------------------------------------------
extern "C" void kernel_launch(void* const* d_in, const int* in_sizes, int n_in,
                              void* d_out, int out_size, void* d_ws, size_t ws_size,
                              hipStream_t stream) {
    const float* query = (const float*)d_in[0];   // [B,1,H]
    const float* value = (const float*)d_in[1];   // [B,S,E]
    const int*   mask  = (const int*)d_in[2];     // [B,1,S]
    const float* W_enc = (const float*)d_in[3];   // [H,E]
    const float* W_q   = (const float*)d_in[4];   // [H,H]
    const float* W_bil = (const float*)d_in[5];   // [H,H]

    float* out = (float*)d_out;
    float* context = out;          // [B,1,E]
    float* alphas  = out + B * E;  // [B,1,S]

    float* ws = (float*)d_ws;
    float* u     = ws;                         // B*E
    float* sc_ws = ws + B * E;                 // B*S
    float* qwp   = ws + B * E + B * S;         // Z2*B*H  (2 MB)
    float* up    = qwp + (size_t)Z2 * B * H;   // Z3*B*E  (2 MB)

    // Chain: high-occupancy split-K partials (no atomics, deterministic)
    k_qwp <<<dim3(H / 256, B, Z2), 256, 0, stream>>>(query, W_q, W_bil, qwp);
    k_up  <<<dim3(E / 256, B, Z3), 256, 0, stream>>>(qwp, W_enc, up);
    k_ured<<<dim3(B * E / 256), 256, 0, stream>>>(up, u);

    // Scores (the 268 MB HBM stream)
    k_scores<<<dim3(S / 16, B), 256, 0, stream>>>(u, value, mask, sc_ws);

    // Softmax + alphas + context
    k_smctx<<<dim3(B), 256, 0, stream>>>(sc_ws, value, alphas, context);
}